// Round 6
// baseline (237.104 us; speedup 1.0000x reference)
//
#include <hip/hip_runtime.h>
#include <cstddef>
#include <cstdint>

#define SEQ    2048
#define NBATCH 2

typedef unsigned short u16;
typedef unsigned int   u32;
typedef __attribute__((ext_vector_type(8))) short bf16x8;  // 8 bf16 = 4 VGPRs
typedef __attribute__((ext_vector_type(4))) short bf16x4;  // 4 bf16 = 2 VGPRs
typedef __attribute__((ext_vector_type(4))) float f32x4;

#if __has_builtin(__builtin_amdgcn_exp2f)
#define EXP2F(x) __builtin_amdgcn_exp2f(x)
#else
#define EXP2F(x) exp2f(x)
#endif

// K=16 bf16 MFMA: v_mfma_f32_16x16x16_bf16 (2-reg A/B), LLVM name ..._1k
#define MFMA_K16(a, b, c) __builtin_amdgcn_mfma_f32_16x16x16bf16_1k(a, b, c, 0, 0, 0)

__device__ __forceinline__ u32 fbits(float x) { union { float f; u32 u; } c; c.f = x; return c.u; }
__device__ __forceinline__ u16 f2bf(float x) { return (u16)((fbits(x) + 0x8000u) >> 16); }
// pack two floats -> (bf16(hi)<<16) | bf16(lo)
__device__ __forceinline__ u32 pack2bf(float lo, float hi) {
    return __builtin_amdgcn_perm(fbits(hi) + 0x8000u, fbits(lo) + 0x8000u, 0x07060302u);
}
__device__ __forceinline__ bf16x4 mk_bf16x4(u32 lo, u32 hi) {
    union { u32 w[2]; bf16x4 v; } u; u.w[0] = lo; u.w[1] = hi; return u.v;
}

// ---------------------------------------------------------------------------
// casts: fp32 -> bf16, 4 elems/thread, multiple tensors per launch (grid.y)
// ---------------------------------------------------------------------------
__global__ __launch_bounds__(256)
void cast3(const float* __restrict__ a, const float* __restrict__ b, const float* __restrict__ c,
           u16* __restrict__ oa, u16* __restrict__ ob, u16* __restrict__ oc, int n4)
{
    const float* s; u16* d;
    if (blockIdx.y == 0)      { s = a; d = oa; }
    else if (blockIdx.y == 1) { s = b; d = ob; }
    else                      { s = c; d = oc; }
    int i = blockIdx.x * 256 + threadIdx.x;
    if (i >= n4) return;
    float4 v = ((const float4*)s)[i];
    uint2 r; r.x = pack2bf(v.x, v.y); r.y = pack2bf(v.z, v.w);
    ((uint2*)d)[i] = r;
}

__global__ __launch_bounds__(256)
void cast4(const float* __restrict__ a, const float* __restrict__ b,
           const float* __restrict__ c, const float* __restrict__ e,
           u16* __restrict__ oa, u16* __restrict__ ob, u16* __restrict__ oc, u16* __restrict__ oe,
           int n4)
{
    const float* s; u16* d;
    if (blockIdx.y == 0)      { s = a; d = oa; }
    else if (blockIdx.y == 1) { s = b; d = ob; }
    else if (blockIdx.y == 2) { s = c; d = oc; }
    else                      { s = e; d = oe; }
    int i = blockIdx.x * 256 + threadIdx.x;
    if (i >= n4) return;
    float4 v = ((const float4*)s)[i];
    uint2 r; r.x = pack2bf(v.x, v.y); r.y = pack2bf(v.z, v.w);
    ((uint2*)d)[i] = r;
}

// ---------------------------------------------------------------------------
// QKV GEMM body (proven): Y = X @ W^T, 128x128 tile, BK=64, reg-prefetch.
// layout 0: Y bf16 plain [m][1024]
// layout 2: Y bf16 transposed-through-LDS to [n,h,d,l]
// ---------------------------------------------------------------------------
__device__ __forceinline__
void gemm_body(const u16* __restrict__ X, const u16* __restrict__ W,
               void* __restrict__ Yv, const int layout)
{
    __shared__ u16 smem[2 * 128 * 72];
    u16* As = smem;
    u16* Bs = smem + 128 * 72;

    const int tid  = threadIdx.x;
    const int wave = tid >> 6;
    const int lane = tid & 63;
    const int lm   = lane & 15;
    const int quad = lane >> 4;
    const int m0 = blockIdx.x * 128;
    const int n0 = blockIdx.y * 128;
    const int wr = (wave & 1) * 64;
    const int wc = (wave >> 1) * 64;

    const int srow = tid >> 1;
    const int scol = (tid & 1) * 32;
    const u16* xg = X + (size_t)(m0 + srow) * 1024 + scol;
    const u16* wg = W + (size_t)(n0 + srow) * 1024 + scol;

    bf16x8 pa[4], pb[4];
    #pragma unroll
    for (int p = 0; p < 4; ++p) {
        pa[p] = *(const bf16x8*)(xg + p * 8);
        pb[p] = *(const bf16x8*)(wg + p * 8);
    }

    f32x4 acc[4][4] = {};

    for (int k0 = 0; k0 < 1024; k0 += 64) {
        __syncthreads();
        #pragma unroll
        for (int p = 0; p < 4; ++p) {
            *(bf16x8*)&As[srow * 72 + scol + p * 8] = pa[p];
            *(bf16x8*)&Bs[srow * 72 + scol + p * 8] = pb[p];
        }
        __syncthreads();
        if (k0 + 64 < 1024) {
            #pragma unroll
            for (int p = 0; p < 4; ++p) {
                pa[p] = *(const bf16x8*)(xg + k0 + 64 + p * 8);
                pb[p] = *(const bf16x8*)(wg + k0 + 64 + p * 8);
            }
        }
        #pragma unroll
        for (int kk = 0; kk < 64; kk += 32) {
            bf16x8 af[4], bf[4];
            #pragma unroll
            for (int t = 0; t < 4; ++t) {
                af[t] = *(const bf16x8*)&As[(wr + t * 16 + lm) * 72 + kk + quad * 8];
                bf[t] = *(const bf16x8*)&Bs[(wc + t * 16 + lm) * 72 + kk + quad * 8];
            }
            #pragma unroll
            for (int i = 0; i < 4; ++i)
                #pragma unroll
                for (int j = 0; j < 4; ++j)
                    acc[i][j] = __builtin_amdgcn_mfma_f32_16x16x32_bf16(af[i], bf[j], acc[i][j], 0, 0, 0);
        }
    }

    if (layout == 0) {
        u16* Y = (u16*)Yv;
        #pragma unroll
        for (int i = 0; i < 4; ++i)
            #pragma unroll
            for (int j = 0; j < 4; ++j) {
                const int C = n0 + wc + j * 16 + lm;
                #pragma unroll
                for (int r = 0; r < 4; ++r) {
                    const int R = m0 + wr + i * 16 + quad * 4 + r;
                    Y[(size_t)R * 1024 + C] = f2bf(acc[i][j][r]);
                }
            }
    } else {
        // transpose 128x128 C-tile through LDS, store [n,h,d,l]
        __syncthreads();
        u16* T = smem;              // [d_local][l_local], stride 132
        #pragma unroll
        for (int i = 0; i < 4; ++i)
            #pragma unroll
            for (int j = 0; j < 4; ++j) {
                const int col = wc + j * 16 + lm;
                const int row = wr + i * 16 + quad * 4;
                uint2 v;
                v.x = pack2bf(acc[i][j][0], acc[i][j][1]);
                v.y = pack2bf(acc[i][j][2], acc[i][j][3]);
                *(uint2*)&T[col * 132 + row] = v;
            }
        __syncthreads();
        const int dp = tid >> 1, half = (tid & 1) * 64;
        const int nn = m0 >> 11, l0 = m0 & 2047;
        const int C = n0 + dp, h = C >> 6, d = C & 63;
        u16* Y = (u16*)Yv;
        const size_t base = (((size_t)nn * 16 + h) * 64 + d) * SEQ + l0 + half;
        #pragma unroll
        for (int p = 0; p < 8; ++p) {
            bf16x8 v = *(const bf16x8*)&T[dp * 132 + half + p * 8];
            *(bf16x8*)(Y + base + p * 8) = v;
        }
    }
}

__global__ __launch_bounds__(256, 2)
void gemm_qkv(const u16* __restrict__ xq, const u16* __restrict__ xk, const u16* __restrict__ xv,
              const u16* __restrict__ wq, const u16* __restrict__ wk, const u16* __restrict__ wv,
              u16* __restrict__ qb, u16* __restrict__ kb, u16* __restrict__ vt)
{
    if (blockIdx.z == 0)      gemm_body(xq, wq, qb, 0);
    else if (blockIdx.z == 1) gemm_body(xk, wk, kb, 0);
    else                      gemm_body(xv, wv, vt, 2);
}

// ---------------------------------------------------------------------------
// Output GEMM: 128x64 tiles -> 512 blocks (2/CU, cross-block barrier cover).
// Y fp32 [m][1024] + bias. Wave = 64x32 (4x2 MFMA tiles).
// ---------------------------------------------------------------------------
__global__ __launch_bounds__(256, 2)
void gemm_out64(const u16* __restrict__ X, const u16* __restrict__ W,
                float* __restrict__ Y, const float* __restrict__ bias)
{
    __shared__ u16 As[128 * 72];
    __shared__ u16 Bs[64 * 72];

    const int tid  = threadIdx.x;
    const int wave = tid >> 6;
    const int lane = tid & 63;
    const int lm   = lane & 15;
    const int quad = lane >> 4;
    const int m0 = blockIdx.x * 128;
    const int n0 = blockIdx.y * 64;
    const int wr = (wave & 1) * 64;
    const int wc = (wave >> 1) * 32;

    const int arow = tid >> 1, acol = (tid & 1) * 32;
    const int brow = tid >> 2, bcol = (tid & 3) * 16;
    const u16* xg = X + (size_t)(m0 + arow) * 1024 + acol;
    const u16* wg = W + (size_t)(n0 + brow) * 1024 + bcol;

    bf16x8 pa[4], pb[2];
    #pragma unroll
    for (int p = 0; p < 4; ++p) pa[p] = *(const bf16x8*)(xg + p * 8);
    #pragma unroll
    for (int p = 0; p < 2; ++p) pb[p] = *(const bf16x8*)(wg + p * 8);

    f32x4 acc[4][2] = {};

    for (int k0 = 0; k0 < 1024; k0 += 64) {
        __syncthreads();
        #pragma unroll
        for (int p = 0; p < 4; ++p) *(bf16x8*)&As[arow * 72 + acol + p * 8] = pa[p];
        #pragma unroll
        for (int p = 0; p < 2; ++p) *(bf16x8*)&Bs[brow * 72 + bcol + p * 8] = pb[p];
        __syncthreads();
        if (k0 + 64 < 1024) {
            #pragma unroll
            for (int p = 0; p < 4; ++p) pa[p] = *(const bf16x8*)(xg + k0 + 64 + p * 8);
            #pragma unroll
            for (int p = 0; p < 2; ++p) pb[p] = *(const bf16x8*)(wg + k0 + 64 + p * 8);
        }
        #pragma unroll
        for (int kk = 0; kk < 64; kk += 32) {
            bf16x8 af[4], bf[2];
            #pragma unroll
            for (int t = 0; t < 4; ++t)
                af[t] = *(const bf16x8*)&As[(wr + t * 16 + lm) * 72 + kk + quad * 8];
            #pragma unroll
            for (int j = 0; j < 2; ++j)
                bf[j] = *(const bf16x8*)&Bs[(wc + j * 16 + lm) * 72 + kk + quad * 8];
            #pragma unroll
            for (int i = 0; i < 4; ++i)
                #pragma unroll
                for (int j = 0; j < 2; ++j)
                    acc[i][j] = __builtin_amdgcn_mfma_f32_16x16x32_bf16(af[i], bf[j], acc[i][j], 0, 0, 0);
        }
    }

    #pragma unroll
    for (int i = 0; i < 4; ++i)
        #pragma unroll
        for (int j = 0; j < 2; ++j) {
            const int C = n0 + wc + j * 16 + lm;
            const float bv = bias[C];
            #pragma unroll
            for (int r = 0; r < 4; ++r) {
                const int R = m0 + wr + i * 16 + quad * 4 + r;
                Y[(size_t)R * 1024 + C] = acc[i][j][r] + bv;
            }
        }
}

// ---------------------------------------------------------------------------
// Flash attention. S^T trick: compute S^T = K·Q^T (A=K-frag, B=Q-frag), whose
// C-layout (key=quad*4+r, q=lm) IS the A-operand layout of the K=16 MFMA —
// so P feeds PV directly from registers, no LDS round-trip.
// Block = 256 thr (4 waves) = 128 q of one (n,h); wave owns 32 q (2 q-tiles).
// Qb,Kb: [n,l,1024] bf16. VT: [n,h,d,l] bf16. O: [n,l,1024] bf16.
// LDS: Ks 18.4K + Vts 17.4K = 35.8K.
// ---------------------------------------------------------------------------
__global__ __launch_bounds__(256, 2)
void flash_attn_bf16(const u16* __restrict__ Qb, const u16* __restrict__ Kb,
                     const u16* __restrict__ VT, const int* __restrict__ mask,
                     u16* __restrict__ O)
{
    __shared__ u16 Ks[128 * 72];      // [key l][d]
    __shared__ u16 Vts[64 * 136];     // [d][key l]

    const int tid  = threadIdx.x;
    const int wave = tid >> 6;
    const int lane = tid & 63;
    const int lm   = lane & 15;
    const int quad = lane >> 4;
    const int h = blockIdx.y, n = blockIdx.z;
    const int wq = blockIdx.x * 128 + wave * 32;

    const u16* Qh = Qb + ((size_t)n * SEQ) * 1024 + h * 64;
    const u16* Kh = Kb + ((size_t)n * SEQ) * 1024 + h * 64;
    const u16* Vh = VT + (((size_t)n * 16 + h) * 64) * SEQ;
    const int* mk = mask + (size_t)n * SEQ;

    // Q fragments resident (B-operand): n=lm -> q, k=quad*8+j -> d
    bf16x8 qf[2][2];
    #pragma unroll
    for (int qt = 0; qt < 2; ++qt)
        #pragma unroll
        for (int ks = 0; ks < 2; ++ks)
            qf[qt][ks] = *(const bf16x8*)(Qh + (size_t)(wq + qt * 16 + lm) * 1024 + ks * 32 + quad * 8);

    f32x4 o_acc[2][4] = {};   // [qt][dt], C-layout q=quad*4+r, d=lm
    float l_i[2] = {};        // per-lane partial row sums, q = qt*16+lm

    // staging coords: K 128 rows x 64 d (2 thr/row); V 64 d x 128 keys (4 thr/row)
    const int kr = tid >> 1, kc = (tid & 1) * 32;
    const int vr = tid >> 2, vc = (tid & 3) * 32;

    bf16x8 ka[4], va[4];
    #pragma unroll
    for (int p = 0; p < 4; ++p) {
        ka[p] = *(const bf16x8*)(Kh + (size_t)kr * 1024 + kc + p * 8);
        va[p] = *(const bf16x8*)(Vh + (size_t)vr * SEQ + vc + p * 8);
    }

    const float cs = 0.125f * 1.44269504f;   // 1/sqrt(64) folded with log2(e)

    for (int c0 = 0; c0 < SEQ; c0 += 128) {
        __syncthreads();   // prior chunk's Ks/Vts reads complete
        #pragma unroll
        for (int p = 0; p < 4; ++p) {
            *(bf16x8*)&Ks[kr * 72 + kc + p * 8]   = ka[p];
            *(bf16x8*)&Vts[vr * 136 + vc + p * 8] = va[p];
        }
        __syncthreads();

        if (c0 + 128 < SEQ) {   // prefetch next chunk; in flight under compute
            #pragma unroll
            for (int p = 0; p < 4; ++p) {
                ka[p] = *(const bf16x8*)(Kh + (size_t)(c0 + 128 + kr) * 1024 + kc + p * 8);
                va[p] = *(const bf16x8*)(Vh + (size_t)vr * SEQ + c0 + 128 + vc + p * 8);
            }
        }

        // mask words for this lane's keys (key = c0 + kt*16 + quad*4 + r)
        int4 mkv[8];
        #pragma unroll
        for (int kt = 0; kt < 8; ++kt)
            mkv[kt] = *(const int4*)(mk + c0 + kt * 16 + quad * 4);

        // ---- S^T = K·Q^T: D[key][q]  (32 MFMAs)
        f32x4 st[8][2] = {};
        #pragma unroll
        for (int kt = 0; kt < 8; ++kt) {
            bf16x8 kf0 = *(const bf16x8*)&Ks[(kt * 16 + lm) * 72 + quad * 8];
            bf16x8 kf1 = *(const bf16x8*)&Ks[(kt * 16 + lm) * 72 + 32 + quad * 8];
            #pragma unroll
            for (int qt = 0; qt < 2; ++qt) {
                st[kt][qt] = __builtin_amdgcn_mfma_f32_16x16x32_bf16(kf0, qf[qt][0], st[kt][qt], 0, 0, 0);
                st[kt][qt] = __builtin_amdgcn_mfma_f32_16x16x32_bf16(kf1, qf[qt][1], st[kt][qt], 0, 0, 0);
            }
        }

        // ---- exp2(scale*s), mask, row-sums, pack to K=16 A-frags (registers!)
        bf16x4 pf[8][2];
        #pragma unroll
        for (int kt = 0; kt < 8; ++kt) {
            const int4 mv = mkv[kt];
            const int mm[4] = {mv.x, mv.y, mv.z, mv.w};
            #pragma unroll
            for (int qt = 0; qt < 2; ++qt) {
                float e[4];
                #pragma unroll
                for (int r = 0; r < 4; ++r) {
                    float v = EXP2F(st[kt][qt][r] * cs);
                    v = mm[r] ? v : 0.0f;
                    e[r] = v;
                    l_i[qt] += v;
                }
                pf[kt][qt] = mk_bf16x4(pack2bf(e[0], e[1]), pack2bf(e[2], e[3]));
            }
        }

        // ---- O += P @ V via K=16 MFMAs: A=pf (regs), B=V-frag (b64 LDS reads)
        #pragma unroll
        for (int kt = 0; kt < 8; ++kt)
            #pragma unroll
            for (int dt = 0; dt < 4; ++dt) {
                bf16x4 vf = *(const bf16x4*)&Vts[(dt * 16 + lm) * 136 + kt * 16 + quad * 4];
                #pragma unroll
                for (int qt = 0; qt < 2; ++qt)
                    o_acc[qt][dt] = MFMA_K16(pf[kt][qt], vf, o_acc[qt][dt]);
            }
    }

    // ---- epilogue: reduce l across quads, redistribute, normalize, store
    float linv[2][4];
    #pragma unroll
    for (int qt = 0; qt < 2; ++qt) {
        float v = l_i[qt];
        v += __shfl_xor(v, 16);
        v += __shfl_xor(v, 32);
        #pragma unroll
        for (int r = 0; r < 4; ++r)
            linv[qt][r] = 1.0f / __shfl(v, quad * 4 + r);
    }
    #pragma unroll
    for (int qt = 0; qt < 2; ++qt)
        #pragma unroll
        for (int dt = 0; dt < 4; ++dt)
            #pragma unroll
            for (int r = 0; r < 4; ++r) {
                const int ql = wq + qt * 16 + quad * 4 + r;
                const int col = h * 64 + dt * 16 + lm;
                O[((size_t)n * SEQ + ql) * 1024 + col] = f2bf(o_acc[qt][dt][r] * linv[qt][r]);
            }
}

// ---------------------------------------------------------------------------
extern "C" void kernel_launch(void* const* d_in, const int* in_sizes, int n_in,
                              void* d_out, int out_size, void* d_ws, size_t ws_size,
                              hipStream_t stream)
{
    const float* values = (const float*)d_in[0];
    const float* keys   = (const float*)d_in[1];
    const float* query  = (const float*)d_in[2];
    const int*   mask   = (const int*)d_in[3];
    const float* W_q    = (const float*)d_in[4];
    const float* W_k    = (const float*)d_in[5];
    const float* W_v    = (const float*)d_in[6];
    const float* W_o    = (const float*)d_in[7];
    const float* b_o    = (const float*)d_in[8];

    const size_t NTOK = (size_t)NBATCH * SEQ * 1024;  // 4194304
    const size_t WSZ  = 1024 * 1024;
    u16* p = (u16*)d_ws;
    u16* qb    = p; p += NTOK;   // q  [n,l,e] bf16
    u16* kb    = p; p += NTOK;   // k  [n,l,e] bf16
    u16* vt    = p; p += NTOK;   // v^T[n,h,d,l] bf16
    u16* xq    = p; p += NTOK;   // bf16 input casts
    u16* xk    = p; p += NTOK;
    u16* xv    = p; p += NTOK;
    u16* attnb = p; p += NTOK;   // attn out [n,l,e] bf16
    u16* wqb   = p; p += WSZ;    // bf16 weight casts
    u16* wkb   = p; p += WSZ;
    u16* wvb   = p; p += WSZ;
    u16* wob   = p; p += WSZ;

    cast3<<<dim3(4096, 3), 256, 0, stream>>>(query, keys, values, xq, xk, xv, (int)(NTOK / 4));
    cast4<<<dim3(1024, 4), 256, 0, stream>>>(W_q, W_k, W_v, W_o, wqb, wkb, wvb, wob, (int)(WSZ / 4));

    gemm_qkv<<<dim3(32, 8, 3), 256, 0, stream>>>(xq, xk, xv, wqb, wkb, wvb, qb, kb, vt);

    flash_attn_bf16<<<dim3(16, 16, 2), 256, 0, stream>>>(qb, kb, vt, mask, attnb);

    gemm_out64<<<dim3(32, 16), 256, 0, stream>>>(attnb, wob, (float*)d_out, b_o);
}

// Round 7
// 228.902 us; speedup vs baseline: 1.0358x; 1.0358x over previous
//
#include <hip/hip_runtime.h>
#include <cstddef>
#include <cstdint>

#define SEQ    2048
#define NBATCH 2

typedef unsigned short u16;
typedef unsigned int   u32;
typedef __attribute__((ext_vector_type(8))) short bf16x8;  // 8 bf16 = 4 VGPRs
typedef __attribute__((ext_vector_type(4))) float f32x4;

#if __has_builtin(__builtin_amdgcn_exp2f)
#define EXP2F(x) __builtin_amdgcn_exp2f(x)
#else
#define EXP2F(x) exp2f(x)
#endif

__device__ __forceinline__ u32 fbits(float x) { union { float f; u32 u; } c; c.f = x; return c.u; }
__device__ __forceinline__ u16 f2bf(float x) { return (u16)((fbits(x) + 0x8000u) >> 16); }
// pack two floats -> (bf16(hi)<<16) | bf16(lo)
__device__ __forceinline__ u32 pack2bf(float lo, float hi) {
    return __builtin_amdgcn_perm(fbits(hi) + 0x8000u, fbits(lo) + 0x8000u, 0x07060302u);
}

// ---------------------------------------------------------------------------
// one cast launch for all 7 tensors. grid (4096, 4):
//   y<3: inputs (1M float4 each). y==3: 4 weights, x>>10 selects tensor.
// ---------------------------------------------------------------------------
__global__ __launch_bounds__(256)
void cast_all(const float* __restrict__ q, const float* __restrict__ k, const float* __restrict__ v,
              const float* __restrict__ wq, const float* __restrict__ wk,
              const float* __restrict__ wv, const float* __restrict__ wo,
              u16* __restrict__ oq, u16* __restrict__ ok, u16* __restrict__ ov,
              u16* __restrict__ owq, u16* __restrict__ owk, u16* __restrict__ owv,
              u16* __restrict__ owo)
{
    const float* s; u16* d; int i;
    if (blockIdx.y == 0)      { s = q; d = oq; i = blockIdx.x * 256 + threadIdx.x; }
    else if (blockIdx.y == 1) { s = k; d = ok; i = blockIdx.x * 256 + threadIdx.x; }
    else if (blockIdx.y == 2) { s = v; d = ov; i = blockIdx.x * 256 + threadIdx.x; }
    else {
        const int w = blockIdx.x >> 10, xi = blockIdx.x & 1023;
        if (w == 0)      { s = wq; d = owq; }
        else if (w == 1) { s = wk; d = owk; }
        else if (w == 2) { s = wv; d = owv; }
        else             { s = wo; d = owo; }
        i = xi * 256 + threadIdx.x;
    }
    float4 vv = ((const float4*)s)[i];
    uint2 r; r.x = pack2bf(vv.x, vv.y); r.y = pack2bf(vv.z, vv.w);
    ((uint2*)d)[i] = r;
}

// ---------------------------------------------------------------------------
// QKV GEMM body (proven): Y = X @ W^T, 128x128 tile, BK=64, reg-prefetch.
// layout 0: Y bf16 plain [m][1024]
// layout 2: Y bf16 transposed-through-LDS to [n,h,d,l]
// ---------------------------------------------------------------------------
__device__ __forceinline__
void gemm_body(const u16* __restrict__ X, const u16* __restrict__ W,
               void* __restrict__ Yv, const int layout)
{
    __shared__ u16 smem[2 * 128 * 72];
    u16* As = smem;
    u16* Bs = smem + 128 * 72;

    const int tid  = threadIdx.x;
    const int wave = tid >> 6;
    const int lane = tid & 63;
    const int lm   = lane & 15;
    const int quad = lane >> 4;
    const int m0 = blockIdx.x * 128;
    const int n0 = blockIdx.y * 128;
    const int wr = (wave & 1) * 64;
    const int wc = (wave >> 1) * 64;

    const int srow = tid >> 1;
    const int scol = (tid & 1) * 32;
    const u16* xg = X + (size_t)(m0 + srow) * 1024 + scol;
    const u16* wg = W + (size_t)(n0 + srow) * 1024 + scol;

    bf16x8 pa[4], pb[4];
    #pragma unroll
    for (int p = 0; p < 4; ++p) {
        pa[p] = *(const bf16x8*)(xg + p * 8);
        pb[p] = *(const bf16x8*)(wg + p * 8);
    }

    f32x4 acc[4][4] = {};

    for (int k0 = 0; k0 < 1024; k0 += 64) {
        __syncthreads();
        #pragma unroll
        for (int p = 0; p < 4; ++p) {
            *(bf16x8*)&As[srow * 72 + scol + p * 8] = pa[p];
            *(bf16x8*)&Bs[srow * 72 + scol + p * 8] = pb[p];
        }
        __syncthreads();
        if (k0 + 64 < 1024) {
            #pragma unroll
            for (int p = 0; p < 4; ++p) {
                pa[p] = *(const bf16x8*)(xg + k0 + 64 + p * 8);
                pb[p] = *(const bf16x8*)(wg + k0 + 64 + p * 8);
            }
        }
        #pragma unroll
        for (int kk = 0; kk < 64; kk += 32) {
            bf16x8 af[4], bf[4];
            #pragma unroll
            for (int t = 0; t < 4; ++t) {
                af[t] = *(const bf16x8*)&As[(wr + t * 16 + lm) * 72 + kk + quad * 8];
                bf[t] = *(const bf16x8*)&Bs[(wc + t * 16 + lm) * 72 + kk + quad * 8];
            }
            #pragma unroll
            for (int i = 0; i < 4; ++i)
                #pragma unroll
                for (int j = 0; j < 4; ++j)
                    acc[i][j] = __builtin_amdgcn_mfma_f32_16x16x32_bf16(af[i], bf[j], acc[i][j], 0, 0, 0);
        }
    }

    if (layout == 0) {
        u16* Y = (u16*)Yv;
        #pragma unroll
        for (int i = 0; i < 4; ++i)
            #pragma unroll
            for (int j = 0; j < 4; ++j) {
                const int C = n0 + wc + j * 16 + lm;
                #pragma unroll
                for (int r = 0; r < 4; ++r) {
                    const int R = m0 + wr + i * 16 + quad * 4 + r;
                    Y[(size_t)R * 1024 + C] = f2bf(acc[i][j][r]);
                }
            }
    } else {
        // transpose 128x128 C-tile through LDS, store [n,h,d,l]
        __syncthreads();
        u16* T = smem;              // [d_local][l_local], stride 132
        #pragma unroll
        for (int i = 0; i < 4; ++i)
            #pragma unroll
            for (int j = 0; j < 4; ++j) {
                const int col = wc + j * 16 + lm;
                const int row = wr + i * 16 + quad * 4;
                uint2 v;
                v.x = pack2bf(acc[i][j][0], acc[i][j][1]);
                v.y = pack2bf(acc[i][j][2], acc[i][j][3]);
                *(uint2*)&T[col * 132 + row] = v;
            }
        __syncthreads();
        const int dp = tid >> 1, half = (tid & 1) * 64;
        const int nn = m0 >> 11, l0 = m0 & 2047;
        const int C = n0 + dp, h = C >> 6, d = C & 63;
        u16* Y = (u16*)Yv;
        const size_t base = (((size_t)nn * 16 + h) * 64 + d) * SEQ + l0 + half;
        #pragma unroll
        for (int p = 0; p < 8; ++p) {
            bf16x8 v = *(const bf16x8*)&T[dp * 132 + half + p * 8];
            *(bf16x8*)(Y + base + p * 8) = v;
        }
    }
}

// 768 blocks = 3/CU; bound regalloc so all three fit (VGPR <= ~170)
__global__ __launch_bounds__(256, 3)
void gemm_qkv(const u16* __restrict__ xq, const u16* __restrict__ xk, const u16* __restrict__ xv,
              const u16* __restrict__ wq, const u16* __restrict__ wk, const u16* __restrict__ wv,
              u16* __restrict__ qb, u16* __restrict__ kb, u16* __restrict__ vt)
{
    if (blockIdx.z == 0)      gemm_body(xq, wq, qb, 0);
    else if (blockIdx.z == 1) gemm_body(xk, wk, kb, 0);
    else                      gemm_body(xv, wv, vt, 2);
}

// ---------------------------------------------------------------------------
// Output GEMM: 128x64 tiles -> 512 blocks (2/CU). Y fp32 [m][1024] + bias.
// ---------------------------------------------------------------------------
__global__ __launch_bounds__(256, 2)
void gemm_out64(const u16* __restrict__ X, const u16* __restrict__ W,
                float* __restrict__ Y, const float* __restrict__ bias)
{
    __shared__ u16 As[128 * 72];
    __shared__ u16 Bs[64 * 72];

    const int tid  = threadIdx.x;
    const int wave = tid >> 6;
    const int lane = tid & 63;
    const int lm   = lane & 15;
    const int quad = lane >> 4;
    const int m0 = blockIdx.x * 128;
    const int n0 = blockIdx.y * 64;
    const int wr = (wave & 1) * 64;
    const int wc = (wave >> 1) * 32;

    const int arow = tid >> 1, acol = (tid & 1) * 32;
    const int brow = tid >> 2, bcol = (tid & 3) * 16;
    const u16* xg = X + (size_t)(m0 + arow) * 1024 + acol;
    const u16* wg = W + (size_t)(n0 + brow) * 1024 + bcol;

    bf16x8 pa[4], pb[2];
    #pragma unroll
    for (int p = 0; p < 4; ++p) pa[p] = *(const bf16x8*)(xg + p * 8);
    #pragma unroll
    for (int p = 0; p < 2; ++p) pb[p] = *(const bf16x8*)(wg + p * 8);

    f32x4 acc[4][2] = {};

    for (int k0 = 0; k0 < 1024; k0 += 64) {
        __syncthreads();
        #pragma unroll
        for (int p = 0; p < 4; ++p) *(bf16x8*)&As[arow * 72 + acol + p * 8] = pa[p];
        #pragma unroll
        for (int p = 0; p < 2; ++p) *(bf16x8*)&Bs[brow * 72 + bcol + p * 8] = pb[p];
        __syncthreads();
        if (k0 + 64 < 1024) {
            #pragma unroll
            for (int p = 0; p < 4; ++p) pa[p] = *(const bf16x8*)(xg + k0 + 64 + p * 8);
            #pragma unroll
            for (int p = 0; p < 2; ++p) pb[p] = *(const bf16x8*)(wg + k0 + 64 + p * 8);
        }
        #pragma unroll
        for (int kk = 0; kk < 64; kk += 32) {
            bf16x8 af[4], bf[2];
            #pragma unroll
            for (int t = 0; t < 4; ++t)
                af[t] = *(const bf16x8*)&As[(wr + t * 16 + lm) * 72 + kk + quad * 8];
            #pragma unroll
            for (int j = 0; j < 2; ++j)
                bf[j] = *(const bf16x8*)&Bs[(wc + j * 16 + lm) * 72 + kk + quad * 8];
            #pragma unroll
            for (int i = 0; i < 4; ++i)
                #pragma unroll
                for (int j = 0; j < 2; ++j)
                    acc[i][j] = __builtin_amdgcn_mfma_f32_16x16x32_bf16(af[i], bf[j], acc[i][j], 0, 0, 0);
        }
    }

    #pragma unroll
    for (int i = 0; i < 4; ++i)
        #pragma unroll
        for (int j = 0; j < 2; ++j) {
            const int C = n0 + wc + j * 16 + lm;
            const float bv = bias[C];
            #pragma unroll
            for (int r = 0; r < 4; ++r) {
                const int R = m0 + wr + i * 16 + quad * 4 + r;
                Y[(size_t)R * 1024 + C] = acc[i][j][r] + bv;
            }
        }
}

// ---------------------------------------------------------------------------
// Flash attention (R4-proven structure): bf16 MFMA, max-free softmax,
// key-chunk 128 with two-half P/PV through wave-private LDS, reg-prefetch.
// XCD swizzle: all 16 q-blocks of one (n,h) share wid%8 -> same XCD L2
// (4 heads/XCD = 4 MB K/V fits the 4 MB L2).
// Qb,Kb: [n,l,1024] bf16.  VT: [n,h,d,l] bf16.  O: [n,l,1024] bf16.
// ---------------------------------------------------------------------------
__global__ __launch_bounds__(256, 2)
void flash_attn_bf16(const u16* __restrict__ Qb, const u16* __restrict__ Kb,
                     const u16* __restrict__ VT, const int* __restrict__ mask,
                     u16* __restrict__ O)
{
    __shared__ u16 Ks[128 * 72];      // [key l][d]
    __shared__ u16 Vts[64 * 136];     // [d][key l]
    __shared__ u16 Ps[4][32 * 72];    // per-wave P [q][key-half]

    const int tid  = threadIdx.x;
    const int wave = tid >> 6;
    const int lane = tid & 63;
    const int lm   = lane & 15;
    const int quad = lane >> 4;

    // XCD-locality decode (perf-only; any mapping is correct)
    const int wid = blockIdx.x + 16 * blockIdx.y + 256 * blockIdx.z;  // 0..511
    const int idx = wid >> 3;
    const int hn  = (wid & 7) + 8 * (idx & 3);    // 0..31
    const int h   = hn & 15, n = hn >> 4;
    const int wq  = (idx >> 2) * 128 + wave * 32;

    const u16* Qh = Qb + ((size_t)n * SEQ) * 1024 + h * 64;
    const u16* Kh = Kb + ((size_t)n * SEQ) * 1024 + h * 64;
    const u16* Vh = VT + (((size_t)n * 16 + h) * 64) * SEQ;
    const int* mk = mask + (size_t)n * SEQ;
    u16* Pw = &Ps[wave][0];

    // Q fragments resident: A-layout m=lm, k=quad*8+j
    bf16x8 qf[2][2];
    #pragma unroll
    for (int t = 0; t < 2; ++t)
        #pragma unroll
        for (int s = 0; s < 2; ++s)
            qf[t][s] = *(const bf16x8*)(Qh + (size_t)(wq + t * 16 + lm) * 1024 + s * 32 + quad * 8);

    f32x4 o_acc[2][4] = {};
    float l_i[2][4] = {};

    // staging coords: K 128 rows x 64 d (2 thr/row); V 64 d x 128 keys (4 thr/row)
    const int kr = tid >> 1, kc = (tid & 1) * 32;
    const int vr = tid >> 2, vc = (tid & 3) * 32;

    bf16x8 ka[4], va[4];
    #pragma unroll
    for (int p = 0; p < 4; ++p) {
        ka[p] = *(const bf16x8*)(Kh + (size_t)kr * 1024 + kc + p * 8);
        va[p] = *(const bf16x8*)(Vh + (size_t)vr * SEQ + vc + p * 8);
    }

    const float cs = 0.125f * 1.44269504f;   // 1/sqrt(64) folded with log2(e)

    for (int c0 = 0; c0 < SEQ; c0 += 128) {
        __syncthreads();   // prior chunk's Ks/Vts reads complete
        #pragma unroll
        for (int p = 0; p < 4; ++p) {
            *(bf16x8*)&Ks[kr * 72 + kc + p * 8]   = ka[p];
            *(bf16x8*)&Vts[vr * 136 + vc + p * 8] = va[p];
        }
        __syncthreads();

        if (c0 + 128 < SEQ) {   // prefetch next chunk; in flight under compute
            #pragma unroll
            for (int p = 0; p < 4; ++p) {
                ka[p] = *(const bf16x8*)(Kh + (size_t)(c0 + 128 + kr) * 1024 + kc + p * 8);
                va[p] = *(const bf16x8*)(Vh + (size_t)vr * SEQ + c0 + 128 + vc + p * 8);
            }
        }

        // ---- S = Q K^T over 128 keys (8 n-tiles, 32 MFMAs)
        f32x4 s[2][8] = {};
        #pragma unroll
        for (int nt = 0; nt < 8; ++nt) {
            bf16x8 kf0 = *(const bf16x8*)&Ks[(nt * 16 + lm) * 72 + quad * 8];
            bf16x8 kf1 = *(const bf16x8*)&Ks[(nt * 16 + lm) * 72 + 32 + quad * 8];
            #pragma unroll
            for (int t = 0; t < 2; ++t) {
                s[t][nt] = __builtin_amdgcn_mfma_f32_16x16x32_bf16(qf[t][0], kf0, s[t][nt], 0, 0, 0);
                s[t][nt] = __builtin_amdgcn_mfma_f32_16x16x32_bf16(qf[t][1], kf1, s[t][nt], 0, 0, 0);
            }
        }

        // ---- exp2(scale*s), mask, row-sum accumulation (max-free)
        int msk[8];
        #pragma unroll
        for (int nt = 0; nt < 8; ++nt) msk[nt] = mk[c0 + nt * 16 + lm];
        #pragma unroll
        for (int t = 0; t < 2; ++t)
            #pragma unroll
            for (int nt = 0; nt < 8; ++nt)
                #pragma unroll
                for (int r = 0; r < 4; ++r) {
                    float e = EXP2F(s[t][nt][r] * cs);
                    e = msk[nt] ? e : 0.0f;
                    s[t][nt][r] = e;
                    l_i[t][r] += e;
                }

        // ---- two key-halves: P -> wave-private LDS, then PV (no barriers)
        #pragma unroll
        for (int half = 0; half < 2; ++half) {
            #pragma unroll
            for (int t = 0; t < 2; ++t)
                #pragma unroll
                for (int ntl = 0; ntl < 4; ++ntl)
                    #pragma unroll
                    for (int r = 0; r < 4; ++r)
                        Pw[(t * 16 + quad * 4 + r) * 72 + ntl * 16 + lm] =
                            f2bf(s[t][half * 4 + ntl][r]);

            #pragma unroll
            for (int ksl = 0; ksl < 2; ++ksl) {
                bf16x8 pf[2];
                #pragma unroll
                for (int t = 0; t < 2; ++t)
                    pf[t] = *(const bf16x8*)&Pw[(t * 16 + lm) * 72 + ksl * 32 + quad * 8];
                #pragma unroll
                for (int dt = 0; dt < 4; ++dt) {
                    bf16x8 vf = *(const bf16x8*)&Vts[(dt * 16 + lm) * 136 + half * 64 + ksl * 32 + quad * 8];
                    #pragma unroll
                    for (int t = 0; t < 2; ++t)
                        o_acc[t][dt] = __builtin_amdgcn_mfma_f32_16x16x32_bf16(pf[t], vf, o_acc[t][dt], 0, 0, 0);
                }
            }
        }
    }

    // ---- epilogue: one l reduction, normalize, store
    #pragma unroll
    for (int t = 0; t < 2; ++t)
        #pragma unroll
        for (int r = 0; r < 4; ++r) {
            float v = l_i[t][r];
            #pragma unroll
            for (int off = 1; off < 16; off <<= 1) v += __shfl_xor(v, off);
            l_i[t][r] = 1.0f / v;
        }
    #pragma unroll
    for (int t = 0; t < 2; ++t)
        #pragma unroll
        for (int dt = 0; dt < 4; ++dt)
            #pragma unroll
            for (int r = 0; r < 4; ++r) {
                const int ql = wq + t * 16 + quad * 4 + r;
                const int col = h * 64 + dt * 16 + lm;
                O[((size_t)n * SEQ + ql) * 1024 + col] = f2bf(o_acc[t][dt][r] * l_i[t][r]);
            }
}

// ---------------------------------------------------------------------------
extern "C" void kernel_launch(void* const* d_in, const int* in_sizes, int n_in,
                              void* d_out, int out_size, void* d_ws, size_t ws_size,
                              hipStream_t stream)
{
    const float* values = (const float*)d_in[0];
    const float* keys   = (const float*)d_in[1];
    const float* query  = (const float*)d_in[2];
    const int*   mask   = (const int*)d_in[3];
    const float* W_q    = (const float*)d_in[4];
    const float* W_k    = (const float*)d_in[5];
    const float* W_v    = (const float*)d_in[6];
    const float* W_o    = (const float*)d_in[7];
    const float* b_o    = (const float*)d_in[8];

    const size_t NTOK = (size_t)NBATCH * SEQ * 1024;  // 4194304
    const size_t WSZ  = 1024 * 1024;
    u16* p = (u16*)d_ws;
    u16* qb    = p; p += NTOK;   // q  [n,l,e] bf16
    u16* kb    = p; p += NTOK;   // k  [n,l,e] bf16
    u16* vt    = p; p += NTOK;   // v^T[n,h,d,l] bf16
    u16* xq    = p; p += NTOK;   // bf16 input casts
    u16* xk    = p; p += NTOK;
    u16* xv    = p; p += NTOK;
    u16* attnb = p; p += NTOK;   // attn out [n,l,e] bf16
    u16* wqb   = p; p += WSZ;    // bf16 weight casts
    u16* wkb   = p; p += WSZ;
    u16* wvb   = p; p += WSZ;
    u16* wob   = p; p += WSZ;

    cast_all<<<dim3(4096, 4), 256, 0, stream>>>(query, keys, values,
                                                W_q, W_k, W_v, W_o,
                                                xq, xk, xv, wqb, wkb, wvb, wob);

    gemm_qkv<<<dim3(32, 8, 3), 256, 0, stream>>>(xq, xk, xv, wqb, wkb, wvb, qb, kb, vt);

    flash_attn_bf16<<<dim3(16, 16, 2), 256, 0, stream>>>(qb, kb, vt, mask, attnb);

    gemm_out64<<<dim3(32, 16), 256, 0, stream>>>(attnb, wob, (float*)d_out, b_o);
}